// Round 10
// baseline (356.266 us; speedup 1.0000x reference)
//
#include <hip/hip_runtime.h>

typedef short bf16x8 __attribute__((ext_vector_type(8)));
typedef unsigned short u16x8 __attribute__((ext_vector_type(8)));
typedef unsigned short u16x4 __attribute__((ext_vector_type(4)));
typedef float f32x4 __attribute__((ext_vector_type(4)));
typedef unsigned u32x4 __attribute__((ext_vector_type(4)));
typedef unsigned u32x2 __attribute__((ext_vector_type(2)));

#define DEV static __device__ __forceinline__

DEV float bf2f(unsigned short u) { return __uint_as_float(((unsigned)u) << 16); }
DEV unsigned short f2bf(float f) {
  unsigned u = __float_as_uint(f);
  return (unsigned short)((u + 0x7fffu + ((u >> 16) & 1u)) >> 16);
}
DEV unsigned cvtpk(float lo, float hi) {
  unsigned r;
  asm("v_cvt_pk_bf16_f32 %0, %1, %2" : "=v"(r) : "v"(lo), "v"(hi));
  return r;
}
DEV void p32swap(unsigned& a, unsigned& b) {
  asm volatile("v_permlane32_swap_b32 %0, %1" : "+v"(a), "+v"(b));
}
DEV void p16swap(unsigned& a, unsigned& b) {
  asm volatile("v_permlane16_swap_b32 %0, %1" : "+v"(a), "+v"(b));
}

#define GLDS16(g, l)                                                                   \
  __builtin_amdgcn_global_load_lds((const __attribute__((address_space(1))) void*)(g), \
                                   (__attribute__((address_space(3))) void*)(l), 16, 0, 0)

// ---------------- fused fp32 -> bf16 converts (all 6 tensors, one launch) ----------------
DEV void cvt_body(const float* __restrict__ src, unsigned short* __restrict__ dst,
                  int rows, int cols, int dstRows, int bid) {
  int i = bid * 256 + (int)threadIdx.x;
  int e = i << 2;
  int r = e / cols;
  int c = e - r * cols;
  u16x4 o = {0, 0, 0, 0};
  if (r < rows) {
    const float* p = src + (size_t)r * cols + c;
    o[0] = f2bf(p[0]); o[1] = f2bf(p[1]); o[2] = f2bf(p[2]); o[3] = f2bf(p[3]);
  }
  *(u16x4*)(dst + e) = o;
}

__global__ __launch_bounds__(256) void convert_all(
    const float* __restrict__ x, const float* __restrict__ w_qa, const float* __restrict__ w_kva,
    const float* __restrict__ w_qb, const float* __restrict__ w_kvb, const float* __restrict__ w_o,
    unsigned short* __restrict__ xb, unsigned short* __restrict__ wqkva,
    unsigned short* __restrict__ wqbb, unsigned short* __restrict__ wkvbb,
    unsigned short* __restrict__ wob) {
  int bid = blockIdx.x;
  if (bid < 8192)        cvt_body(x,     xb,                        4096, 2048, 4096, bid);
  else if (bid < 11264)  cvt_body(w_qa,  wqkva,                     1536, 2048, 1536, bid - 8192);
  else if (bid < 12544)  cvt_body(w_kva, wqkva + (size_t)1536*2048,  576, 2048,  640, bid - 11264);
  else if (bid < 15616)  cvt_body(w_qb,  wqbb,                      2048, 1536, 2048, bid - 12544);
  else if (bid < 17152)  cvt_body(w_kvb, wkvbb,                     3072,  512, 3072, bid - 15616);
  else                   cvt_body(w_o,   wob,                       2048, 2048, 2048, bid - 17152);
}

// ---------------- bf16 GEMM: C[M,N] = A[M,K] @ B[N,K]^T  (m97 structure) ----------------
template <typename OutT>
__global__ __launch_bounds__(256, 2) void gemm_bt(const unsigned short* __restrict__ A,
                                                  const unsigned short* __restrict__ B,
                                                  OutT* __restrict__ C, int M, int N, int K) {
  __shared__ __align__(16) unsigned short As[128 * 64];
  __shared__ __align__(16) unsigned short Bs[128 * 64];
  const int tid = threadIdx.x;
  const int lane = tid & 63, wave = tid >> 6;
  const int l16 = lane & 15, lhi = lane >> 4;
  const int nbn = N >> 7;
  const int bm = blockIdx.x / nbn, bn = blockIdx.x - bm * nbn;
  const int m0 = bm << 7, n0 = bn << 7;
  const int wm = (wave >> 1) << 6, wn = (wave & 1) << 6;
  f32x4 acc[4][4] = {};
  for (int k0 = 0; k0 < K; k0 += 64) {
#pragma unroll
    for (int it = 0; it < 4; ++it) {
      int slot = it * 256 + tid;
      int row = slot >> 3, col = (slot & 7) << 3;
      GLDS16(A + (size_t)(m0 + row) * K + k0 + col, As + (it * 256 + wave * 64) * 8);
      GLDS16(B + (size_t)(n0 + row) * K + k0 + col, Bs + (it * 256 + wave * 64) * 8);
    }
    __syncthreads();
#pragma unroll
    for (int ks = 0; ks < 2; ++ks) {
      bf16x8 a[4], b[4];
#pragma unroll
      for (int i = 0; i < 4; ++i) {
        a[i] = *(const bf16x8*)(As + (wm + i * 16 + l16) * 64 + ks * 32 + lhi * 8);
        b[i] = *(const bf16x8*)(Bs + (wn + i * 16 + l16) * 64 + ks * 32 + lhi * 8);
      }
#pragma unroll
      for (int i = 0; i < 4; ++i)
#pragma unroll
        for (int j = 0; j < 4; ++j)
          acc[i][j] = __builtin_amdgcn_mfma_f32_16x16x32_bf16(a[i], b[j], acc[i][j], 0, 0, 0);
    }
    __syncthreads();
  }
#pragma unroll
  for (int i = 0; i < 4; ++i)
#pragma unroll
    for (int j = 0; j < 4; ++j)
#pragma unroll
      for (int r = 0; r < 4; ++r) {
        int row = m0 + wm + i * 16 + lhi * 4 + r;
        int col = n0 + wn + j * 16 + l16;
        float v = acc[i][j][r];
        if constexpr (sizeof(OutT) == 4)
          C[(size_t)row * N + col] = v;
        else
          C[(size_t)row * N + col] = (OutT)f2bf(v);
      }
}

// ---------------- kvb GEMM: writes K-content cols to kvfull, V cols transposed to VT ----------------
__global__ __launch_bounds__(256, 2) void gemm_kvb(const unsigned short* __restrict__ A,  // kv_c [4096][512]
                                                   const unsigned short* __restrict__ B,  // wkvbb [3072][512]
                                                   unsigned short* __restrict__ kvfull,   // [4096][3072] (k cols only)
                                                   unsigned short* __restrict__ VT) {     // [B][16][128][2048]
  const int M = 4096, N = 3072, K = 512;
  __shared__ __align__(16) unsigned short As[128 * 64];
  __shared__ __align__(16) unsigned short Bs[128 * 64];
  const int tid = threadIdx.x;
  const int lane = tid & 63, wave = tid >> 6;
  const int l16 = lane & 15, lhi = lane >> 4;
  const int nbn = N >> 7;
  const int bm = blockIdx.x / nbn, bn = blockIdx.x - bm * nbn;
  const int m0 = bm << 7, n0 = bn << 7;
  const int wm = (wave >> 1) << 6, wn = (wave & 1) << 6;
  f32x4 acc[4][4] = {};
  for (int k0 = 0; k0 < K; k0 += 64) {
#pragma unroll
    for (int it = 0; it < 4; ++it) {
      int slot = it * 256 + tid;
      int row = slot >> 3, col = (slot & 7) << 3;
      GLDS16(A + (size_t)(m0 + row) * K + k0 + col, As + (it * 256 + wave * 64) * 8);
      GLDS16(B + (size_t)(n0 + row) * K + k0 + col, Bs + (it * 256 + wave * 64) * 8);
    }
    __syncthreads();
#pragma unroll
    for (int ks = 0; ks < 2; ++ks) {
      bf16x8 a[4], b[4];
#pragma unroll
      for (int i = 0; i < 4; ++i) {
        a[i] = *(const bf16x8*)(As + (wm + i * 16 + l16) * 64 + ks * 32 + lhi * 8);
        b[i] = *(const bf16x8*)(Bs + (wn + i * 16 + l16) * 64 + ks * 32 + lhi * 8);
      }
#pragma unroll
      for (int i = 0; i < 4; ++i)
#pragma unroll
        for (int j = 0; j < 4; ++j)
          acc[i][j] = __builtin_amdgcn_mfma_f32_16x16x32_bf16(a[i], b[j], acc[i][j], 0, 0, 0);
    }
    __syncthreads();
  }
#pragma unroll
  for (int i = 0; i < 4; ++i)
#pragma unroll
    for (int j = 0; j < 4; ++j) {
      int col = n0 + wn + j * 16 + l16;
      int h = col / 192;
      int jc = col - h * 192;
      int row0 = m0 + wm + i * 16 + lhi * 4;
      if (jc < 64) {
#pragma unroll
        for (int r = 0; r < 4; ++r)
          kvfull[(size_t)(row0 + r) * 3072 + col] = f2bf(acc[i][j][r]);
      } else {
        int d = jc - 64;
        int b = row0 >> 11, t0 = row0 & 2047;
        u16x4 pk;
#pragma unroll
        for (int r = 0; r < 4; ++r) pk[r] = f2bf(acc[i][j][r]);
        *(u16x4*)(VT + ((size_t)((b * 16 + h) * 128 + d)) * 2048 + t0) = pk;
      }
    }
}

// ---------------- fused RMS norms: q (1536) + kv (512) + RoPE of shared k_rope ----------------
__global__ __launch_bounds__(256) void rms_fused(const unsigned short* __restrict__ qkva,
                                                 const float* __restrict__ qw,
                                                 const float* __restrict__ kvw,
                                                 unsigned short* __restrict__ q_c,
                                                 unsigned short* __restrict__ kv_c,
                                                 unsigned short* __restrict__ krope) {
  const int row = blockIdx.x, tid = threadIdx.x;
  const unsigned short* p = qkva + (size_t)row * 2176;
  float fq[8];
  float ssq = 0.f;
  const bool act = tid < 192;
  if (act) {
    u16x8 v = *(const u16x8*)(p + tid * 8);
#pragma unroll
    for (int j = 0; j < 8; ++j) { fq[j] = bf2f(v[j]); ssq += fq[j] * fq[j]; }
  }
  float f0 = bf2f(p[1536 + tid * 2]), f1 = bf2f(p[1536 + tid * 2 + 1]);
  float sskv = f0 * f0 + f1 * f1;
#pragma unroll
  for (int m = 1; m <= 32; m <<= 1) {
    ssq += __shfl_xor(ssq, m);
    sskv += __shfl_xor(sskv, m);
  }
  __shared__ float rq[4], rkv[4];
  if ((tid & 63) == 0) { rq[tid >> 6] = ssq; rkv[tid >> 6] = sskv; }
  __syncthreads();
  float rstdq = rsqrtf((rq[0] + rq[1] + rq[2] + rq[3]) * (1.f / 1536.f) + 1e-6f);
  float rstdkv = rsqrtf((rkv[0] + rkv[1] + rkv[2] + rkv[3]) * (1.f / 512.f) + 1e-6f);
  if (act) {
    u16x8 o;
#pragma unroll
    for (int j = 0; j < 8; ++j) o[j] = f2bf(fq[j] * rstdq * qw[tid * 8 + j]);
    *(u16x8*)(q_c + (size_t)row * 1536 + tid * 8) = o;
  }
  kv_c[(size_t)row * 512 + tid * 2]     = f2bf(f0 * rstdkv * kvw[tid * 2]);
  kv_c[(size_t)row * 512 + tid * 2 + 1] = f2bf(f1 * rstdkv * kvw[tid * 2 + 1]);
  if (tid < 32) {
    int j = tid;
    float xr = bf2f(p[2048 + 2 * j]), xi = bf2f(p[2048 + 2 * j + 1]);
    int t = row & 2047;
    float ang = (float)t * powf(10000.f, -(float)j * (1.f / 32.f));
    float c = cosf(ang), s = sinf(ang);
    krope[(size_t)row * 64 + 2 * j]     = f2bf(xr * c - xi * s);
    krope[(size_t)row * 64 + 2 * j + 1] = f2bf(xr * s + xi * c);
  }
}

// ---------------- causal flash attention: R5 structure + T14 async-STAGE split ----------------
// 1024 blocks (64 q-rows each), 4 waves x 16 q. K,V single-buffered in LDS (32KB).
// T14: at tile kt, ISSUE global_load_dwordx4 for tile kt+1 into 32 VGPRs (no wait);
// compute kt from LDS (hides L2/HBM latency); barrier; ds_write regs -> LDS (waitcnt
// lands here, mostly satisfied); barrier. Same XOR-swizzled layout (writes swizzled
// directly — reg path needs no pre-swizzled source). R5 dispatch map (balanced 66
// tiles / 4 blocks per CU). Swapped-QK^T, exp2 softmax, defer-max, in-register P.
__global__ __launch_bounds__(256, 4) void flash_attn(const unsigned short* __restrict__ qfull,
                                                     const unsigned short* __restrict__ kvfull, // [4096][3072]
                                                     const unsigned short* __restrict__ krope,  // [4096][64]
                                                     const unsigned short* __restrict__ Vt,     // [B][H][128][2048]
                                                     unsigned short* __restrict__ out) {
  const int tid = threadIdx.x, lane = tid & 63, wave = tid >> 6;
  const int l16 = lane & 15, lhi = lane >> 4;
  const int bid = blockIdx.x;
  const int xcd = bid & 7, Lb = bid >> 3;      // Lb 0..127 within XCD chunk
  const int bhl = Lb >> 5, cL = Lb & 31;
  const int s = (bhl & 1) ? (31 - cL) : cL;    // R5 map: per-CU 4 blocks, 66 tiles
  const int bh = xcd * 4 + bhl;
  const int h = bh & 15, b = bh >> 4;
  __shared__ __align__(16) unsigned short Ks[64 * 128];
  __shared__ __align__(16) unsigned short Vs[128 * 64];

  // --- Q fragment: 16 q-rows (this wave), RoPE on d>=64, fold (1/8)*log2(e) ---
  const float QSCALE = 0.125f * 1.44269504089f;
  bf16x8 qf[4];
  f32x4 o_acc[8] = {};
  const int qg = s * 64 + wave * 16 + l16;
  {
    const unsigned short* qrow = qfull + (size_t)(b * 2048 + qg) * 2048 + h * 128;
#pragma unroll
    for (int ks = 0; ks < 4; ++ks) {
      u16x8 raw = *(const u16x8*)(qrow + ks * 32 + lhi * 8);
      float f[8];
#pragma unroll
      for (int j = 0; j < 8; ++j) f[j] = bf2f(raw[j]);
      if (ks >= 2) {
#pragma unroll
        for (int pp = 0; pp < 4; ++pp) {
          int d = ks * 32 + lhi * 8 + 2 * pp;
          int jl = (d - 64) >> 1;
          float ang = (float)qg * powf(10000.f, -(float)jl * (1.f / 32.f));
          float co = cosf(ang), si = sinf(ang);
          float xr = f[2 * pp], xi = f[2 * pp + 1];
          f[2 * pp] = xr * co - xi * si;
          f[2 * pp + 1] = xr * si + xi * co;
        }
      }
      bf16x8 fr;
#pragma unroll
      for (int j = 0; j < 8; ++j) fr[j] = (short)f2bf(f[j] * QSCALE);
      qf[ks] = fr;
    }
  }
  float m_run = -1e30f, l_run = 0.f;

  const int bT = b * 2048;
  const unsigned short* Vbh = Vt + (size_t)(b * 16 + h) * 128 * 2048;

  // --- T14 staging state: per-thread 64B of K and 64B of V in registers ---
  u32x4 kr0, kr1, kr2, kr3, vr0, vr1, vr2, vr3;
  auto loadK = [&](int kt, u32x4& d0, u32x4& d1, u32x4& d2, u32x4& d3) {
    u32x4* dsts[4] = {&d0, &d1, &d2, &d3};
#pragma unroll
    for (int it = 0; it < 4; ++it) {
      int Lo = it * 4096 + wave * 1024 + lane * 16;
      int r = Lo >> 8;
      int w = (Lo & 255) ^ ((r & 7) << 4);
      int cc = w >> 1;
      int tl = bT + kt * 64 + r;
      const unsigned short* src = (cc < 64) ? kvfull + (size_t)tl * 3072 + h * 192 + cc
                                            : krope + (size_t)tl * 64 + (cc - 64);
      *dsts[it] = *(const u32x4*)src;
    }
  };
  auto loadV = [&](int kt, u32x4& d0, u32x4& d1, u32x4& d2, u32x4& d3) {
    u32x4* dsts[4] = {&d0, &d1, &d2, &d3};
#pragma unroll
    for (int it = 0; it < 4; ++it) {
      int Lo = it * 4096 + wave * 1024 + lane * 16;
      int d = Lo >> 7;
      int w = (Lo & 127) ^ ((d & 7) << 4);
      *dsts[it] = *(const u32x4*)(Vbh + (size_t)d * 2048 + kt * 64 + (w >> 1));
    }
  };
  auto writeKV = [&]() {
#pragma unroll
    for (int it = 0; it < 4; ++it) {
      int off = it * 4096 + wave * 1024 + lane * 16;
      u32x4 kv_ = (it == 0) ? kr0 : (it == 1) ? kr1 : (it == 2) ? kr2 : kr3;
      u32x4 vv_ = (it == 0) ? vr0 : (it == 1) ? vr1 : (it == 2) ? vr2 : vr3;
      *(u32x4*)((char*)Ks + off) = kv_;
      *(u32x4*)((char*)Vs + off) = vv_;
    }
  };

  loadK(0, kr0, kr1, kr2, kr3);
  loadV(0, vr0, vr1, vr2, vr3);
  writeKV();
  __syncthreads();

  for (int kt = 0; kt <= s; ++kt) {
    // issue next tile's loads NOW; latency hides under this tile's compute
    if (kt < s) {
      loadK(kt + 1, kr0, kr1, kr2, kr3);
      loadV(kt + 1, vr0, vr1, vr2, vr3);
    }

    // --- S^T = K @ Q^T (lane: col = q = l16; rows k = nt*16 + lhi*4 + r) ---
    f32x4 st[4] = {};
    __builtin_amdgcn_s_setprio(1);
#pragma unroll
    for (int ks = 0; ks < 4; ++ks) {
#pragma unroll
      for (int nt = 0; nt < 4; ++nt) {
        int row = nt * 16 + l16;
        int byteoff = row * 256 + ((ks * 64 + lhi * 16) ^ ((l16 & 7) << 4));
        bf16x8 kf = *(const bf16x8*)((const char*)Ks + byteoff);
        st[nt] = __builtin_amdgcn_mfma_f32_16x16x32_bf16(kf, qf[ks], st[nt], 0, 0, 0);
      }
    }
    __builtin_amdgcn_s_setprio(0);

    // --- softmax (exp2 domain, defer-max) + in-register P fragments ---
    if (kt == s) {  // diagonal: causal mask
#pragma unroll
      for (int nt = 0; nt < 4; ++nt)
#pragma unroll
        for (int r = 0; r < 4; ++r) {
          int kg = kt * 64 + nt * 16 + lhi * 4 + r;
          st[nt][r] = (kg <= qg) ? st[nt][r] : -1e30f;
        }
    }
    float mx = -1e30f;
#pragma unroll
    for (int nt = 0; nt < 4; ++nt)
#pragma unroll
      for (int r = 0; r < 4; ++r) mx = fmaxf(mx, st[nt][r]);
    mx = fmaxf(mx, __shfl_xor(mx, 16));
    mx = fmaxf(mx, __shfl_xor(mx, 32));
    if (__ballot(mx > m_run + 8.f)) {
      float mnew = fmaxf(m_run, mx);
      float sc = exp2f(m_run - mnew);
      m_run = mnew;
      l_run *= sc;
#pragma unroll
      for (int dt = 0; dt < 8; ++dt) o_acc[dt] *= sc;
    }
    const float mcur = m_run;
    float sum = 0.f;
#pragma unroll
    for (int nt = 0; nt < 4; ++nt)
#pragma unroll
      for (int r = 0; r < 4; ++r) {
        float p = exp2f(st[nt][r] - mcur);
        st[nt][r] = p;
        sum += p;
      }
    sum += __shfl_xor(sum, 16);
    sum += __shfl_xor(sum, 32);
    l_run += sum;
    bf16x8 pw[2];
    {
      unsigned pk01[4], pk23[4];
#pragma unroll
      for (int nt = 0; nt < 4; ++nt) {
        pk01[nt] = cvtpk(st[nt][0], st[nt][1]);
        pk23[nt] = cvtpk(st[nt][2], st[nt][3]);
      }
#pragma unroll
      for (int k2 = 0; k2 < 2; ++k2) {
        unsigned a0 = pk01[2 * k2], b0 = pk01[2 * k2 + 1];
        unsigned a1 = pk23[2 * k2], b1 = pk23[2 * k2 + 1];
        p32swap(a0, b0); p16swap(a0, b0);
        p32swap(a1, b1); p16swap(a1, b1);
        u32x4 t4 = {a0, a1, b0, b1};
        pw[k2] = *(bf16x8*)&t4;
      }
    }

    // --- O^T += V^T @ P (lane: col = q = l16; rows d) ---
    __builtin_amdgcn_s_setprio(1);
#pragma unroll
    for (int k2 = 0; k2 < 2; ++k2)
#pragma unroll
      for (int dt = 0; dt < 8; ++dt) {
        int row = dt * 16 + l16;
        int byteoff = row * 128 + ((k2 * 64 + lhi * 16) ^ ((l16 & 7) << 4));
        bf16x8 vf = *(const bf16x8*)((const char*)Vs + byteoff);
        o_acc[dt] = __builtin_amdgcn_mfma_f32_16x16x32_bf16(vf, pw[k2], o_acc[dt], 0, 0, 0);
      }
    __builtin_amdgcn_s_setprio(0);

    __syncthreads();  // all reads of Ks/Vs done
    if (kt < s) {
      writeKV();       // compiler waits vmcnt here; latency already covered
      __syncthreads(); // writes visible to all waves
    }
  }

  // --- epilogue: lane holds O^T[d = dt*16+lhi*4+r][q=l16] ---
  {
    float inv = 1.0f / l_run;
    unsigned short* orow = out + (size_t)(b * 2048 + qg) * 2048 + h * 128;
#pragma unroll
    for (int dt = 0; dt < 8; ++dt) {
      unsigned w01 = cvtpk(o_acc[dt][0] * inv, o_acc[dt][1] * inv);
      unsigned w23 = cvtpk(o_acc[dt][2] * inv, o_acc[dt][3] * inv);
      u32x2 st2 = {w01, w23};
      *(u32x2*)(orow + dt * 16 + lhi * 4) = st2;
    }
  }
}

// =====================================================================================
extern "C" void kernel_launch(void* const* d_in, const int* in_sizes, int n_in,
                              void* d_out, int out_size, void* d_ws, size_t ws_size,
                              hipStream_t stream) {
  (void)in_sizes; (void)n_in; (void)out_size; (void)ws_size;
  const float* x      = (const float*)d_in[0];
  const float* w_qa   = (const float*)d_in[2];
  const float* qa_nw  = (const float*)d_in[3];
  const float* w_qb   = (const float*)d_in[4];
  const float* w_kva  = (const float*)d_in[5];
  const float* kva_nw = (const float*)d_in[6];
  const float* w_kvb  = (const float*)d_in[7];
  const float* w_o    = (const float*)d_in[8];
  float* out = (float*)d_out;
  char* ws = (char*)d_ws;

  unsigned short* xb     = (unsigned short*)(ws + 0);
  unsigned short* wqkva  = (unsigned short*)(ws + 16777216);   // [2176][2048]
  unsigned short* wqbb   = (unsigned short*)(ws + 25690112);
  unsigned short* wkvbb  = (unsigned short*)(ws + 31981568);
  unsigned short* wob    = (unsigned short*)(ws + 35127296);
  unsigned short* qkva   = (unsigned short*)(ws + 43515904);   // [4096][2176]
  unsigned short* qfull  = (unsigned short*)(ws + 43515904);   // alias (qkva dead after rms)
  unsigned short* q_c    = (unsigned short*)(ws + 61341696);   // [4096][1536]
  unsigned short* kv_c   = (unsigned short*)(ws + 73924608);   // [4096][512]
  unsigned short* krope  = (unsigned short*)(ws + 78118912);   // [4096][64]
  unsigned short* attno  = (unsigned short*)(ws + 61341696);   // alias (q_c+kv_c dead)
  unsigned short* Vattn  = (unsigned short*)(ws + 78643200);   // [B][H][128][2048]
  unsigned short* kvfull = (unsigned short*)d_out;             // scratch in d_out (k cols only)

  convert_all<<<21248, 256, 0, stream>>>(x, w_qa, w_kva, w_qb, w_kvb, w_o,
                                         xb, wqkva, wqbb, wkvbb, wob);

  gemm_bt<unsigned short><<<32 * 17, 256, 0, stream>>>(xb, wqkva, qkva, 4096, 2176, 2048);

  rms_fused<<<4096, 256, 0, stream>>>(qkva, qa_nw, kva_nw, q_c, kv_c, krope);

  gemm_bt<unsigned short><<<32 * 16, 256, 0, stream>>>(q_c, wqbb, qfull, 4096, 2048, 1536);
  gemm_kvb<<<32 * 24, 256, 0, stream>>>(kv_c, wkvbb, kvfull, Vattn);

  flash_attn<<<1024, 256, 0, stream>>>(qfull, kvfull, krope, Vattn, attno);

  gemm_bt<float><<<32 * 16, 256, 0, stream>>>(attno, wob, out, 4096, 2048, 2048);
}

// Round 11
// 285.686 us; speedup vs baseline: 1.2471x; 1.2471x over previous
//
#include <hip/hip_runtime.h>

typedef short bf16x8 __attribute__((ext_vector_type(8)));
typedef unsigned short u16x8 __attribute__((ext_vector_type(8)));
typedef unsigned short u16x4 __attribute__((ext_vector_type(4)));
typedef float f32x4 __attribute__((ext_vector_type(4)));
typedef unsigned u32x4 __attribute__((ext_vector_type(4)));
typedef unsigned u32x2 __attribute__((ext_vector_type(2)));

#define DEV static __device__ __forceinline__

DEV float bf2f(unsigned short u) { return __uint_as_float(((unsigned)u) << 16); }
DEV unsigned short f2bf(float f) {
  unsigned u = __float_as_uint(f);
  return (unsigned short)((u + 0x7fffu + ((u >> 16) & 1u)) >> 16);
}
DEV unsigned cvtpk(float lo, float hi) {
  unsigned r;
  asm("v_cvt_pk_bf16_f32 %0, %1, %2" : "=v"(r) : "v"(lo), "v"(hi));
  return r;
}
DEV void p32swap(unsigned& a, unsigned& b) {
  asm volatile("v_permlane32_swap_b32 %0, %1" : "+v"(a), "+v"(b));
}
DEV void p16swap(unsigned& a, unsigned& b) {
  asm volatile("v_permlane16_swap_b32 %0, %1" : "+v"(a), "+v"(b));
}

#define GLDS16(g, l)                                                                   \
  __builtin_amdgcn_global_load_lds((const __attribute__((address_space(1))) void*)(g), \
                                   (__attribute__((address_space(3))) void*)(l), 16, 0, 0)

// ---------------- fused fp32 -> bf16 converts (all 6 tensors, one launch) ----------------
DEV void cvt_body(const float* __restrict__ src, unsigned short* __restrict__ dst,
                  int rows, int cols, int dstRows, int bid) {
  int i = bid * 256 + (int)threadIdx.x;
  int e = i << 2;
  int r = e / cols;
  int c = e - r * cols;
  u16x4 o = {0, 0, 0, 0};
  if (r < rows) {
    const float* p = src + (size_t)r * cols + c;
    o[0] = f2bf(p[0]); o[1] = f2bf(p[1]); o[2] = f2bf(p[2]); o[3] = f2bf(p[3]);
  }
  *(u16x4*)(dst + e) = o;
}

__global__ __launch_bounds__(256) void convert_all(
    const float* __restrict__ x, const float* __restrict__ w_qa, const float* __restrict__ w_kva,
    const float* __restrict__ w_qb, const float* __restrict__ w_kvb, const float* __restrict__ w_o,
    unsigned short* __restrict__ xb, unsigned short* __restrict__ wqkva,
    unsigned short* __restrict__ wqbb, unsigned short* __restrict__ wkvbb,
    unsigned short* __restrict__ wob) {
  int bid = blockIdx.x;
  if (bid < 8192)        cvt_body(x,     xb,                        4096, 2048, 4096, bid);
  else if (bid < 11264)  cvt_body(w_qa,  wqkva,                     1536, 2048, 1536, bid - 8192);
  else if (bid < 12544)  cvt_body(w_kva, wqkva + (size_t)1536*2048,  576, 2048,  640, bid - 11264);
  else if (bid < 15616)  cvt_body(w_qb,  wqbb,                      2048, 1536, 2048, bid - 12544);
  else if (bid < 17152)  cvt_body(w_kvb, wkvbb,                     3072,  512, 3072, bid - 15616);
  else                   cvt_body(w_o,   wob,                       2048, 2048, 2048, bid - 17152);
}

// ---------------- bf16 GEMM: C[M,N] = A[M,K] @ B[N,K]^T  (m97 structure) ----------------
template <typename OutT>
__global__ __launch_bounds__(256, 2) void gemm_bt(const unsigned short* __restrict__ A,
                                                  const unsigned short* __restrict__ B,
                                                  OutT* __restrict__ C, int M, int N, int K) {
  __shared__ __align__(16) unsigned short As[128 * 64];
  __shared__ __align__(16) unsigned short Bs[128 * 64];
  const int tid = threadIdx.x;
  const int lane = tid & 63, wave = tid >> 6;
  const int l16 = lane & 15, lhi = lane >> 4;
  const int nbn = N >> 7;
  const int bm = blockIdx.x / nbn, bn = blockIdx.x - bm * nbn;
  const int m0 = bm << 7, n0 = bn << 7;
  const int wm = (wave >> 1) << 6, wn = (wave & 1) << 6;
  f32x4 acc[4][4] = {};
  for (int k0 = 0; k0 < K; k0 += 64) {
#pragma unroll
    for (int it = 0; it < 4; ++it) {
      int slot = it * 256 + tid;
      int row = slot >> 3, col = (slot & 7) << 3;
      GLDS16(A + (size_t)(m0 + row) * K + k0 + col, As + (it * 256 + wave * 64) * 8);
      GLDS16(B + (size_t)(n0 + row) * K + k0 + col, Bs + (it * 256 + wave * 64) * 8);
    }
    __syncthreads();
#pragma unroll
    for (int ks = 0; ks < 2; ++ks) {
      bf16x8 a[4], b[4];
#pragma unroll
      for (int i = 0; i < 4; ++i) {
        a[i] = *(const bf16x8*)(As + (wm + i * 16 + l16) * 64 + ks * 32 + lhi * 8);
        b[i] = *(const bf16x8*)(Bs + (wn + i * 16 + l16) * 64 + ks * 32 + lhi * 8);
      }
#pragma unroll
      for (int i = 0; i < 4; ++i)
#pragma unroll
        for (int j = 0; j < 4; ++j)
          acc[i][j] = __builtin_amdgcn_mfma_f32_16x16x32_bf16(a[i], b[j], acc[i][j], 0, 0, 0);
    }
    __syncthreads();
  }
#pragma unroll
  for (int i = 0; i < 4; ++i)
#pragma unroll
    for (int j = 0; j < 4; ++j)
#pragma unroll
      for (int r = 0; r < 4; ++r) {
        int row = m0 + wm + i * 16 + lhi * 4 + r;
        int col = n0 + wn + j * 16 + l16;
        float v = acc[i][j][r];
        if constexpr (sizeof(OutT) == 4)
          C[(size_t)row * N + col] = v;
        else
          C[(size_t)row * N + col] = (OutT)f2bf(v);
      }
}

// ---------------- kvb GEMM: writes K-content cols to kvfull, V cols transposed to VT ----------------
__global__ __launch_bounds__(256, 2) void gemm_kvb(const unsigned short* __restrict__ A,  // kv_c [4096][512]
                                                   const unsigned short* __restrict__ B,  // wkvbb [3072][512]
                                                   unsigned short* __restrict__ kvfull,   // [4096][3072] (k cols only)
                                                   unsigned short* __restrict__ VT) {     // [B][16][128][2048]
  const int M = 4096, N = 3072, K = 512;
  __shared__ __align__(16) unsigned short As[128 * 64];
  __shared__ __align__(16) unsigned short Bs[128 * 64];
  const int tid = threadIdx.x;
  const int lane = tid & 63, wave = tid >> 6;
  const int l16 = lane & 15, lhi = lane >> 4;
  const int nbn = N >> 7;
  const int bm = blockIdx.x / nbn, bn = blockIdx.x - bm * nbn;
  const int m0 = bm << 7, n0 = bn << 7;
  const int wm = (wave >> 1) << 6, wn = (wave & 1) << 6;
  f32x4 acc[4][4] = {};
  for (int k0 = 0; k0 < K; k0 += 64) {
#pragma unroll
    for (int it = 0; it < 4; ++it) {
      int slot = it * 256 + tid;
      int row = slot >> 3, col = (slot & 7) << 3;
      GLDS16(A + (size_t)(m0 + row) * K + k0 + col, As + (it * 256 + wave * 64) * 8);
      GLDS16(B + (size_t)(n0 + row) * K + k0 + col, Bs + (it * 256 + wave * 64) * 8);
    }
    __syncthreads();
#pragma unroll
    for (int ks = 0; ks < 2; ++ks) {
      bf16x8 a[4], b[4];
#pragma unroll
      for (int i = 0; i < 4; ++i) {
        a[i] = *(const bf16x8*)(As + (wm + i * 16 + l16) * 64 + ks * 32 + lhi * 8);
        b[i] = *(const bf16x8*)(Bs + (wn + i * 16 + l16) * 64 + ks * 32 + lhi * 8);
      }
#pragma unroll
      for (int i = 0; i < 4; ++i)
#pragma unroll
        for (int j = 0; j < 4; ++j)
          acc[i][j] = __builtin_amdgcn_mfma_f32_16x16x32_bf16(a[i], b[j], acc[i][j], 0, 0, 0);
    }
    __syncthreads();
  }
#pragma unroll
  for (int i = 0; i < 4; ++i)
#pragma unroll
    for (int j = 0; j < 4; ++j) {
      int col = n0 + wn + j * 16 + l16;
      int h = col / 192;
      int jc = col - h * 192;
      int row0 = m0 + wm + i * 16 + lhi * 4;
      if (jc < 64) {
#pragma unroll
        for (int r = 0; r < 4; ++r)
          kvfull[(size_t)(row0 + r) * 3072 + col] = f2bf(acc[i][j][r]);
      } else {
        int d = jc - 64;
        int b = row0 >> 11, t0 = row0 & 2047;
        u16x4 pk;
#pragma unroll
        for (int r = 0; r < 4; ++r) pk[r] = f2bf(acc[i][j][r]);
        *(u16x4*)(VT + ((size_t)((b * 16 + h) * 128 + d)) * 2048 + t0) = pk;
      }
    }
}

// ---------------- fused RMS norms: q (1536) + kv (512) + RoPE of shared k_rope ----------------
__global__ __launch_bounds__(256) void rms_fused(const unsigned short* __restrict__ qkva,
                                                 const float* __restrict__ qw,
                                                 const float* __restrict__ kvw,
                                                 unsigned short* __restrict__ q_c,
                                                 unsigned short* __restrict__ kv_c,
                                                 unsigned short* __restrict__ krope) {
  const int row = blockIdx.x, tid = threadIdx.x;
  const unsigned short* p = qkva + (size_t)row * 2176;
  float fq[8];
  float ssq = 0.f;
  const bool act = tid < 192;
  if (act) {
    u16x8 v = *(const u16x8*)(p + tid * 8);
#pragma unroll
    for (int j = 0; j < 8; ++j) { fq[j] = bf2f(v[j]); ssq += fq[j] * fq[j]; }
  }
  float f0 = bf2f(p[1536 + tid * 2]), f1 = bf2f(p[1536 + tid * 2 + 1]);
  float sskv = f0 * f0 + f1 * f1;
#pragma unroll
  for (int m = 1; m <= 32; m <<= 1) {
    ssq += __shfl_xor(ssq, m);
    sskv += __shfl_xor(sskv, m);
  }
  __shared__ float rq[4], rkv[4];
  if ((tid & 63) == 0) { rq[tid >> 6] = ssq; rkv[tid >> 6] = sskv; }
  __syncthreads();
  float rstdq = rsqrtf((rq[0] + rq[1] + rq[2] + rq[3]) * (1.f / 1536.f) + 1e-6f);
  float rstdkv = rsqrtf((rkv[0] + rkv[1] + rkv[2] + rkv[3]) * (1.f / 512.f) + 1e-6f);
  if (act) {
    u16x8 o;
#pragma unroll
    for (int j = 0; j < 8; ++j) o[j] = f2bf(fq[j] * rstdq * qw[tid * 8 + j]);
    *(u16x8*)(q_c + (size_t)row * 1536 + tid * 8) = o;
  }
  kv_c[(size_t)row * 512 + tid * 2]     = f2bf(f0 * rstdkv * kvw[tid * 2]);
  kv_c[(size_t)row * 512 + tid * 2 + 1] = f2bf(f1 * rstdkv * kvw[tid * 2 + 1]);
  if (tid < 32) {
    int j = tid;
    float xr = bf2f(p[2048 + 2 * j]), xi = bf2f(p[2048 + 2 * j + 1]);
    int t = row & 2047;
    float ang = (float)t * powf(10000.f, -(float)j * (1.f / 32.f));
    float c = cosf(ang), s = sinf(ang);
    krope[(size_t)row * 64 + 2 * j]     = f2bf(xr * c - xi * s);
    krope[(size_t)row * 64 + 2 * j + 1] = f2bf(xr * s + xi * c);
  }
}

// ---------------- causal flash attention (R5 structure, proven 92us) ----------------
// 1024 blocks: one 64-row q-block each; 4 waves x 16 q-rows. Single-buffered K/V
// (32KB LDS) + __launch_bounds__(256,4) -> 4 independent blocks/CU; TLP hides staging.
// Swapped-QK^T, in-register softmax (exp2, defer-max), P in registers via
// cvt_pk+permlane, O^T = mfma(V^T, P). R5 dispatch map: XCD chunks, s / 31-s
// alternating -> per-CU work ~constant, 4 (b,h) groups per XCD stay L2-resident.
// NEW vs R5: staging pointers precomputed per (lane,it) and advanced by fixed
// strides per tile (kt-invariant select + address math hoisted out of the loop).
__global__ __launch_bounds__(256, 4) void flash_attn(const unsigned short* __restrict__ qfull,
                                                     const unsigned short* __restrict__ kvfull, // [4096][3072]
                                                     const unsigned short* __restrict__ krope,  // [4096][64]
                                                     const unsigned short* __restrict__ Vt,     // [B][H][128][2048]
                                                     unsigned short* __restrict__ out) {
  const int tid = threadIdx.x, lane = tid & 63, wave = tid >> 6;
  const int l16 = lane & 15, lhi = lane >> 4;
  const int bid = blockIdx.x;
  const int xcd = bid & 7, Lb = bid >> 3;      // Lb 0..127 within XCD chunk
  const int bhl = Lb >> 5, cL = Lb & 31;
  const int s = (bhl & 1) ? (31 - cL) : cL;    // alternate s / 31-s (R5 map)
  const int bh = xcd * 4 + bhl;
  const int h = bh & 15, b = bh >> 4;
  __shared__ __align__(16) unsigned short Ks[64 * 128];
  __shared__ __align__(16) unsigned short Vs[128 * 64];

  // --- Q fragment: 16 q-rows (this wave), RoPE on d>=64, fold (1/8)*log2(e) ---
  const float QSCALE = 0.125f * 1.44269504089f;
  bf16x8 qf[4];
  f32x4 o_acc[8] = {};
  const int qg = s * 64 + wave * 16 + l16;
  {
    const unsigned short* qrow = qfull + (size_t)(b * 2048 + qg) * 2048 + h * 128;
#pragma unroll
    for (int ks = 0; ks < 4; ++ks) {
      u16x8 raw = *(const u16x8*)(qrow + ks * 32 + lhi * 8);
      float f[8];
#pragma unroll
      for (int j = 0; j < 8; ++j) f[j] = bf2f(raw[j]);
      if (ks >= 2) {
#pragma unroll
        for (int pp = 0; pp < 4; ++pp) {
          int d = ks * 32 + lhi * 8 + 2 * pp;
          int jl = (d - 64) >> 1;
          float ang = (float)qg * powf(10000.f, -(float)jl * (1.f / 32.f));
          float co = cosf(ang), si = sinf(ang);
          float xr = f[2 * pp], xi = f[2 * pp + 1];
          f[2 * pp] = xr * co - xi * si;
          f[2 * pp + 1] = xr * si + xi * co;
        }
      }
      bf16x8 fr;
#pragma unroll
      for (int j = 0; j < 8; ++j) fr[j] = (short)f2bf(f[j] * QSCALE);
      qf[ks] = fr;
    }
  }
  float m_run = -1e30f, l_run = 0.f;

  const int bT = b * 2048;
  const unsigned short* Vbh = Vt + (size_t)(b * 16 + h) * 128 * 2048;

  // --- precompute staging pointers (kt-invariant lane mapping; advance by stride) ---
  const unsigned short* pK[4];
  const unsigned short* pV[4];
  int sKst[4];
#pragma unroll
  for (int it = 0; it < 4; ++it) {
    int Lo = it * 4096 + wave * 1024 + lane * 16;
    int r = Lo >> 8;
    int w = (Lo & 255) ^ ((r & 7) << 4);
    int cc = w >> 1;
    if (cc < 64) { pK[it] = kvfull + (size_t)(bT + r) * 3072 + h * 192 + cc; sKst[it] = 64 * 3072; }
    else         { pK[it] = krope  + (size_t)(bT + r) * 64 + (cc - 64);      sKst[it] = 64 * 64; }
    int d = Lo >> 7;
    int w2 = (Lo & 127) ^ ((d & 7) << 4);
    pV[it] = Vbh + (size_t)d * 2048 + (w2 >> 1);  // advances by 64 elems per tile
  }

  for (int kt = 0; kt <= s; ++kt) {
    // --- stage K and V^T (linear LDS dest; pre-swizzled per-lane global src) ---
#pragma unroll
    for (int it = 0; it < 4; ++it) {
      GLDS16(pK[it], Ks + ((it * 4096 + wave * 1024) >> 1));
      pK[it] += sKst[it];
    }
#pragma unroll
    for (int it = 0; it < 4; ++it) {
      GLDS16(pV[it], Vs + ((it * 4096 + wave * 1024) >> 1));
      pV[it] += 64;
    }
    __syncthreads();  // vmcnt drain: staged tile visible

    // --- S^T = K @ Q^T (lane: col = q = l16; rows k = nt*16 + lhi*4 + r) ---
    f32x4 st[4] = {};
    __builtin_amdgcn_s_setprio(1);
#pragma unroll
    for (int ks = 0; ks < 4; ++ks) {
#pragma unroll
      for (int nt = 0; nt < 4; ++nt) {
        int row = nt * 16 + l16;
        int byteoff = row * 256 + ((ks * 64 + lhi * 16) ^ ((l16 & 7) << 4));
        bf16x8 kf = *(const bf16x8*)((const char*)Ks + byteoff);
        st[nt] = __builtin_amdgcn_mfma_f32_16x16x32_bf16(kf, qf[ks], st[nt], 0, 0, 0);
      }
    }
    __builtin_amdgcn_s_setprio(0);

    // --- softmax (exp2 domain, defer-max), P fragments in registers ---
    if (kt == s) {  // diagonal: causal mask
#pragma unroll
      for (int nt = 0; nt < 4; ++nt)
#pragma unroll
        for (int r = 0; r < 4; ++r) {
          int kg = kt * 64 + nt * 16 + lhi * 4 + r;
          st[nt][r] = (kg <= qg) ? st[nt][r] : -1e30f;
        }
    }
    float mx = -1e30f;
#pragma unroll
    for (int nt = 0; nt < 4; ++nt)
#pragma unroll
      for (int r = 0; r < 4; ++r) mx = fmaxf(mx, st[nt][r]);
    mx = fmaxf(mx, __shfl_xor(mx, 16));
    mx = fmaxf(mx, __shfl_xor(mx, 32));
    if (__ballot(mx > m_run + 8.f)) {
      float mnew = fmaxf(m_run, mx);
      float sc = exp2f(m_run - mnew);
      m_run = mnew;
      l_run *= sc;
#pragma unroll
      for (int dt = 0; dt < 8; ++dt) o_acc[dt] *= sc;
    }
    const float mcur = m_run;
    float sum = 0.f;
#pragma unroll
    for (int nt = 0; nt < 4; ++nt)
#pragma unroll
      for (int r = 0; r < 4; ++r) {
        float p = exp2f(st[nt][r] - mcur);
        st[nt][r] = p;
        sum += p;
      }
    sum += __shfl_xor(sum, 16);
    sum += __shfl_xor(sum, 32);
    l_run += sum;
    bf16x8 pw[2];
    {
      unsigned pk01[4], pk23[4];
#pragma unroll
      for (int nt = 0; nt < 4; ++nt) {
        pk01[nt] = cvtpk(st[nt][0], st[nt][1]);
        pk23[nt] = cvtpk(st[nt][2], st[nt][3]);
      }
#pragma unroll
      for (int k2 = 0; k2 < 2; ++k2) {
        unsigned a0 = pk01[2 * k2], b0 = pk01[2 * k2 + 1];
        unsigned a1 = pk23[2 * k2], b1 = pk23[2 * k2 + 1];
        p32swap(a0, b0); p16swap(a0, b0);
        p32swap(a1, b1); p16swap(a1, b1);
        u32x4 t4 = {a0, a1, b0, b1};
        pw[k2] = *(bf16x8*)&t4;
      }
    }

    // --- O^T += V^T @ P (lane: col = q = l16; rows d) ---
    __builtin_amdgcn_s_setprio(1);
#pragma unroll
    for (int k2 = 0; k2 < 2; ++k2)
#pragma unroll
      for (int dt = 0; dt < 8; ++dt) {
        int row = dt * 16 + l16;
        int byteoff = row * 128 + ((k2 * 64 + lhi * 16) ^ ((l16 & 7) << 4));
        bf16x8 vf = *(const bf16x8*)((const char*)Vs + byteoff);
        o_acc[dt] = __builtin_amdgcn_mfma_f32_16x16x32_bf16(vf, pw[k2], o_acc[dt], 0, 0, 0);
      }
    __builtin_amdgcn_s_setprio(0);

    __syncthreads();  // all reads of Ks/Vs done before next stage overwrites
  }

  // --- epilogue: lane holds O^T[d = dt*16+lhi*4+r][q=l16] ---
  {
    float inv = 1.0f / l_run;
    unsigned short* orow = out + (size_t)(b * 2048 + qg) * 2048 + h * 128;
#pragma unroll
    for (int dt = 0; dt < 8; ++dt) {
      unsigned w01 = cvtpk(o_acc[dt][0] * inv, o_acc[dt][1] * inv);
      unsigned w23 = cvtpk(o_acc[dt][2] * inv, o_acc[dt][3] * inv);
      u32x2 st2 = {w01, w23};
      *(u32x2*)(orow + dt * 16 + lhi * 4) = st2;
    }
  }
}

// =====================================================================================
extern "C" void kernel_launch(void* const* d_in, const int* in_sizes, int n_in,
                              void* d_out, int out_size, void* d_ws, size_t ws_size,
                              hipStream_t stream) {
  (void)in_sizes; (void)n_in; (void)out_size; (void)ws_size;
  const float* x      = (const float*)d_in[0];
  const float* w_qa   = (const float*)d_in[2];
  const float* qa_nw  = (const float*)d_in[3];
  const float* w_qb   = (const float*)d_in[4];
  const float* w_kva  = (const float*)d_in[5];
  const float* kva_nw = (const float*)d_in[6];
  const float* w_kvb  = (const float*)d_in[7];
  const float* w_o    = (const float*)d_in[8];
  float* out = (float*)d_out;
  char* ws = (char*)d_ws;

  unsigned short* xb     = (unsigned short*)(ws + 0);
  unsigned short* wqkva  = (unsigned short*)(ws + 16777216);   // [2176][2048]
  unsigned short* wqbb   = (unsigned short*)(ws + 25690112);
  unsigned short* wkvbb  = (unsigned short*)(ws + 31981568);
  unsigned short* wob    = (unsigned short*)(ws + 35127296);
  unsigned short* qkva   = (unsigned short*)(ws + 43515904);   // [4096][2176]
  unsigned short* qfull  = (unsigned short*)(ws + 43515904);   // alias (qkva dead after rms)
  unsigned short* q_c    = (unsigned short*)(ws + 61341696);   // [4096][1536]
  unsigned short* kv_c   = (unsigned short*)(ws + 73924608);   // [4096][512]
  unsigned short* krope  = (unsigned short*)(ws + 78118912);   // [4096][64]
  unsigned short* attno  = (unsigned short*)(ws + 61341696);   // alias (q_c+kv_c dead)
  unsigned short* Vattn  = (unsigned short*)(ws + 78643200);   // [B][H][128][2048]
  unsigned short* kvfull = (unsigned short*)d_out;             // scratch in d_out (k cols only)

  convert_all<<<21248, 256, 0, stream>>>(x, w_qa, w_kva, w_qb, w_kvb, w_o,
                                         xb, wqkva, wqbb, wkvbb, wob);

  gemm_bt<unsigned short><<<32 * 17, 256, 0, stream>>>(xb, wqkva, qkva, 4096, 2176, 2048);

  rms_fused<<<4096, 256, 0, stream>>>(qkva, qa_nw, kva_nw, q_c, kv_c, krope);

  gemm_bt<unsigned short><<<32 * 16, 256, 0, stream>>>(q_c, wqbb, qfull, 4096, 2048, 1536);
  gemm_kvb<<<32 * 24, 256, 0, stream>>>(kv_c, wkvbb, kvfull, Vattn);

  flash_attn<<<1024, 256, 0, stream>>>(qfull, kvfull, krope, Vattn, attno);

  gemm_bt<float><<<32 * 16, 256, 0, stream>>>(attno, wob, out, 4096, 2048, 2048);
}

// Round 12
// 285.295 us; speedup vs baseline: 1.2488x; 1.0014x over previous
//
#include <hip/hip_runtime.h>

typedef short bf16x8 __attribute__((ext_vector_type(8)));
typedef unsigned short u16x8 __attribute__((ext_vector_type(8)));
typedef unsigned short u16x4 __attribute__((ext_vector_type(4)));
typedef float f32x4 __attribute__((ext_vector_type(4)));
typedef unsigned u32x4 __attribute__((ext_vector_type(4)));
typedef unsigned u32x2 __attribute__((ext_vector_type(2)));

#define DEV static __device__ __forceinline__

DEV float bf2f(unsigned short u) { return __uint_as_float(((unsigned)u) << 16); }
DEV unsigned short f2bf(float f) {
  unsigned u = __float_as_uint(f);
  return (unsigned short)((u + 0x7fffu + ((u >> 16) & 1u)) >> 16);
}
DEV unsigned cvtpk(float lo, float hi) {
  unsigned r;
  asm("v_cvt_pk_bf16_f32 %0, %1, %2" : "=v"(r) : "v"(lo), "v"(hi));
  return r;
}
DEV void p32swap(unsigned& a, unsigned& b) {
  asm volatile("v_permlane32_swap_b32 %0, %1" : "+v"(a), "+v"(b));
}
DEV void p16swap(unsigned& a, unsigned& b) {
  asm volatile("v_permlane16_swap_b32 %0, %1" : "+v"(a), "+v"(b));
}

#define GLDS16(g, l)                                                                   \
  __builtin_amdgcn_global_load_lds((const __attribute__((address_space(1))) void*)(g), \
                                   (__attribute__((address_space(3))) void*)(l), 16, 0, 0)

// ---------------- fused fp32 -> bf16 converts (all 6 tensors, one launch) ----------------
DEV void cvt_body(const float* __restrict__ src, unsigned short* __restrict__ dst,
                  int rows, int cols, int dstRows, int bid) {
  int i = bid * 256 + (int)threadIdx.x;
  int e = i << 2;
  int r = e / cols;
  int c = e - r * cols;
  u16x4 o = {0, 0, 0, 0};
  if (r < rows) {
    const float* p = src + (size_t)r * cols + c;
    o[0] = f2bf(p[0]); o[1] = f2bf(p[1]); o[2] = f2bf(p[2]); o[3] = f2bf(p[3]);
  }
  *(u16x4*)(dst + e) = o;
}

__global__ __launch_bounds__(256) void convert_all(
    const float* __restrict__ x, const float* __restrict__ w_qa, const float* __restrict__ w_kva,
    const float* __restrict__ w_qb, const float* __restrict__ w_kvb, const float* __restrict__ w_o,
    unsigned short* __restrict__ xb, unsigned short* __restrict__ wqkva,
    unsigned short* __restrict__ wqbb, unsigned short* __restrict__ wkvbb,
    unsigned short* __restrict__ wob) {
  int bid = blockIdx.x;
  if (bid < 8192)        cvt_body(x,     xb,                        4096, 2048, 4096, bid);
  else if (bid < 11264)  cvt_body(w_qa,  wqkva,                     1536, 2048, 1536, bid - 8192);
  else if (bid < 12544)  cvt_body(w_kva, wqkva + (size_t)1536*2048,  576, 2048,  640, bid - 11264);
  else if (bid < 15616)  cvt_body(w_qb,  wqbb,                      2048, 1536, 2048, bid - 12544);
  else if (bid < 17152)  cvt_body(w_kvb, wkvbb,                     3072,  512, 3072, bid - 15616);
  else                   cvt_body(w_o,   wob,                       2048, 2048, 2048, bid - 17152);
}

// ---------------- GEMM body: C[M,N] = A[M,K] @ B[N,K]^T, C^T-fragment epilogue ----------------
// mfma(b, a): lane holds row = m0+wm+i*16+l16, cols = n0+wn+j*16+lhi*4+{0..3}
// -> 16 vector stores/thread (u32x2 bf16 / f32x4 fp32) instead of 64 scalar stores.
template <typename OutT>
DEV void gemm_bt_body(const unsigned short* __restrict__ A, const unsigned short* __restrict__ B,
                      OutT* __restrict__ C, int M, int N, int K, int bidx,
                      unsigned short* As, unsigned short* Bs) {
  const int tid = threadIdx.x;
  const int lane = tid & 63, wave = tid >> 6;
  const int l16 = lane & 15, lhi = lane >> 4;
  const int nbn = N >> 7;
  const int bm = bidx / nbn, bn = bidx - bm * nbn;
  const int m0 = bm << 7, n0 = bn << 7;
  const int wm = (wave >> 1) << 6, wn = (wave & 1) << 6;
  f32x4 acc[4][4] = {};
  for (int k0 = 0; k0 < K; k0 += 64) {
#pragma unroll
    for (int it = 0; it < 4; ++it) {
      int slot = it * 256 + tid;
      int row = slot >> 3, col = (slot & 7) << 3;
      GLDS16(A + (size_t)(m0 + row) * K + k0 + col, As + (it * 256 + wave * 64) * 8);
      GLDS16(B + (size_t)(n0 + row) * K + k0 + col, Bs + (it * 256 + wave * 64) * 8);
    }
    __syncthreads();
#pragma unroll
    for (int ks = 0; ks < 2; ++ks) {
      bf16x8 a[4], b[4];
#pragma unroll
      for (int i = 0; i < 4; ++i) {
        a[i] = *(const bf16x8*)(As + (wm + i * 16 + l16) * 64 + ks * 32 + lhi * 8);
        b[i] = *(const bf16x8*)(Bs + (wn + i * 16 + l16) * 64 + ks * 32 + lhi * 8);
      }
#pragma unroll
      for (int i = 0; i < 4; ++i)
#pragma unroll
        for (int j = 0; j < 4; ++j)
          acc[i][j] = __builtin_amdgcn_mfma_f32_16x16x32_bf16(b[j], a[i], acc[i][j], 0, 0, 0);
    }
    __syncthreads();
  }
#pragma unroll
  for (int i = 0; i < 4; ++i)
#pragma unroll
    for (int j = 0; j < 4; ++j) {
      int row = m0 + wm + i * 16 + l16;
      int col0 = n0 + wn + j * 16 + lhi * 4;
      if constexpr (sizeof(OutT) == 4) {
        f32x4 v = {acc[i][j][0], acc[i][j][1], acc[i][j][2], acc[i][j][3]};
        *(f32x4*)((float*)C + (size_t)row * N + col0) = v;
      } else {
        u32x2 v = {cvtpk(acc[i][j][0], acc[i][j][1]), cvtpk(acc[i][j][2], acc[i][j][3])};
        *(u32x2*)((unsigned short*)C + (size_t)row * N + col0) = v;
      }
    }
}

template <typename OutT>
__global__ __launch_bounds__(256, 2) void gemm_bt(const unsigned short* __restrict__ A,
                                                  const unsigned short* __restrict__ B,
                                                  OutT* __restrict__ C, int M, int N, int K) {
  __shared__ __align__(16) unsigned short As[128 * 64];
  __shared__ __align__(16) unsigned short Bs[128 * 64];
  gemm_bt_body<OutT>(A, B, C, M, N, K, blockIdx.x, As, Bs);
}

// ---------------- kvb GEMM body: K-content cols -> kvfull, V cols transposed -> VT ----------------
// Keeps original operand order: its VT store exploits rows-in-lane (4 consecutive t = 8B).
DEV void gemm_kvb_body(const unsigned short* __restrict__ A,  // kv_c [4096][512]
                       const unsigned short* __restrict__ B,  // wkvbb [3072][512]
                       unsigned short* __restrict__ kvfull,   // [4096][3072] (k cols only)
                       unsigned short* __restrict__ VT,       // [B][16][128][2048]
                       int bidx, unsigned short* As, unsigned short* Bs) {
  const int N = 3072, K = 512;
  const int tid = threadIdx.x;
  const int lane = tid & 63, wave = tid >> 6;
  const int l16 = lane & 15, lhi = lane >> 4;
  const int nbn = N >> 7;
  const int bm = bidx / nbn, bn = bidx - bm * nbn;
  const int m0 = bm << 7, n0 = bn << 7;
  const int wm = (wave >> 1) << 6, wn = (wave & 1) << 6;
  f32x4 acc[4][4] = {};
  for (int k0 = 0; k0 < K; k0 += 64) {
#pragma unroll
    for (int it = 0; it < 4; ++it) {
      int slot = it * 256 + tid;
      int row = slot >> 3, col = (slot & 7) << 3;
      GLDS16(A + (size_t)(m0 + row) * K + k0 + col, As + (it * 256 + wave * 64) * 8);
      GLDS16(B + (size_t)(n0 + row) * K + k0 + col, Bs + (it * 256 + wave * 64) * 8);
    }
    __syncthreads();
#pragma unroll
    for (int ks = 0; ks < 2; ++ks) {
      bf16x8 a[4], b[4];
#pragma unroll
      for (int i = 0; i < 4; ++i) {
        a[i] = *(const bf16x8*)(As + (wm + i * 16 + l16) * 64 + ks * 32 + lhi * 8);
        b[i] = *(const bf16x8*)(Bs + (wn + i * 16 + l16) * 64 + ks * 32 + lhi * 8);
      }
#pragma unroll
      for (int i = 0; i < 4; ++i)
#pragma unroll
        for (int j = 0; j < 4; ++j)
          acc[i][j] = __builtin_amdgcn_mfma_f32_16x16x32_bf16(a[i], b[j], acc[i][j], 0, 0, 0);
    }
    __syncthreads();
  }
#pragma unroll
  for (int i = 0; i < 4; ++i)
#pragma unroll
    for (int j = 0; j < 4; ++j) {
      int col = n0 + wn + j * 16 + l16;
      int h = col / 192;
      int jc = col - h * 192;
      int row0 = m0 + wm + i * 16 + lhi * 4;
      if (jc < 64) {
#pragma unroll
        for (int r = 0; r < 4; ++r)
          kvfull[(size_t)(row0 + r) * 3072 + col] = f2bf(acc[i][j][r]);
      } else {
        int d = jc - 64;
        int b = row0 >> 11, t0 = row0 & 2047;
        u16x4 pk;
#pragma unroll
        for (int r = 0; r < 4; ++r) pk[r] = f2bf(acc[i][j][r]);
        *(u16x4*)(VT + ((size_t)((b * 16 + h) * 128 + d)) * 2048 + t0) = pk;
      }
    }
}

// ---------------- merged up-projections: blocks 0..511 = qb GEMM, 512..1279 = kvb GEMM ----------------
__global__ __launch_bounds__(256, 2) void gemm_up(const unsigned short* __restrict__ q_c,
                                                  const unsigned short* __restrict__ wqbb,
                                                  unsigned short* __restrict__ qfull,
                                                  const unsigned short* __restrict__ kv_c,
                                                  const unsigned short* __restrict__ wkvbb,
                                                  unsigned short* __restrict__ kvfull,
                                                  unsigned short* __restrict__ VT) {
  __shared__ __align__(16) unsigned short As[128 * 64];
  __shared__ __align__(16) unsigned short Bs[128 * 64];
  if (blockIdx.x < 512)
    gemm_bt_body<unsigned short>(q_c, wqbb, qfull, 4096, 2048, 1536, blockIdx.x, As, Bs);
  else
    gemm_kvb_body(kv_c, wkvbb, kvfull, VT, blockIdx.x - 512, As, Bs);
}

// ---------------- fused RMS norms: q (1536) + kv (512) + RoPE of shared k_rope ----------------
__global__ __launch_bounds__(256) void rms_fused(const unsigned short* __restrict__ qkva,
                                                 const float* __restrict__ qw,
                                                 const float* __restrict__ kvw,
                                                 unsigned short* __restrict__ q_c,
                                                 unsigned short* __restrict__ kv_c,
                                                 unsigned short* __restrict__ krope) {
  const int row = blockIdx.x, tid = threadIdx.x;
  const unsigned short* p = qkva + (size_t)row * 2176;
  float fq[8];
  float ssq = 0.f;
  const bool act = tid < 192;
  if (act) {
    u16x8 v = *(const u16x8*)(p + tid * 8);
#pragma unroll
    for (int j = 0; j < 8; ++j) { fq[j] = bf2f(v[j]); ssq += fq[j] * fq[j]; }
  }
  float f0 = bf2f(p[1536 + tid * 2]), f1 = bf2f(p[1536 + tid * 2 + 1]);
  float sskv = f0 * f0 + f1 * f1;
#pragma unroll
  for (int m = 1; m <= 32; m <<= 1) {
    ssq += __shfl_xor(ssq, m);
    sskv += __shfl_xor(sskv, m);
  }
  __shared__ float rq[4], rkv[4];
  if ((tid & 63) == 0) { rq[tid >> 6] = ssq; rkv[tid >> 6] = sskv; }
  __syncthreads();
  float rstdq = rsqrtf((rq[0] + rq[1] + rq[2] + rq[3]) * (1.f / 1536.f) + 1e-6f);
  float rstdkv = rsqrtf((rkv[0] + rkv[1] + rkv[2] + rkv[3]) * (1.f / 512.f) + 1e-6f);
  if (act) {
    u16x8 o;
#pragma unroll
    for (int j = 0; j < 8; ++j) o[j] = f2bf(fq[j] * rstdq * qw[tid * 8 + j]);
    *(u16x8*)(q_c + (size_t)row * 1536 + tid * 8) = o;
  }
  kv_c[(size_t)row * 512 + tid * 2]     = f2bf(f0 * rstdkv * kvw[tid * 2]);
  kv_c[(size_t)row * 512 + tid * 2 + 1] = f2bf(f1 * rstdkv * kvw[tid * 2 + 1]);
  if (tid < 32) {
    int j = tid;
    float xr = bf2f(p[2048 + 2 * j]), xi = bf2f(p[2048 + 2 * j + 1]);
    int t = row & 2047;
    float ang = (float)t * powf(10000.f, -(float)j * (1.f / 32.f));
    float c = cosf(ang), s = sinf(ang);
    krope[(size_t)row * 64 + 2 * j]     = f2bf(xr * c - xi * s);
    krope[(size_t)row * 64 + 2 * j + 1] = f2bf(xr * s + xi * c);
  }
}

// ---------------- causal flash attention (R5 structure, proven ~93us; unchanged) ----------------
__global__ __launch_bounds__(256, 4) void flash_attn(const unsigned short* __restrict__ qfull,
                                                     const unsigned short* __restrict__ kvfull, // [4096][3072]
                                                     const unsigned short* __restrict__ krope,  // [4096][64]
                                                     const unsigned short* __restrict__ Vt,     // [B][H][128][2048]
                                                     unsigned short* __restrict__ out) {
  const int tid = threadIdx.x, lane = tid & 63, wave = tid >> 6;
  const int l16 = lane & 15, lhi = lane >> 4;
  const int bid = blockIdx.x;
  const int xcd = bid & 7, Lb = bid >> 3;
  const int bhl = Lb >> 5, cL = Lb & 31;
  const int s = (bhl & 1) ? (31 - cL) : cL;
  const int bh = xcd * 4 + bhl;
  const int h = bh & 15, b = bh >> 4;
  __shared__ __align__(16) unsigned short Ks[64 * 128];
  __shared__ __align__(16) unsigned short Vs[128 * 64];

  const float QSCALE = 0.125f * 1.44269504089f;
  bf16x8 qf[4];
  f32x4 o_acc[8] = {};
  const int qg = s * 64 + wave * 16 + l16;
  {
    const unsigned short* qrow = qfull + (size_t)(b * 2048 + qg) * 2048 + h * 128;
#pragma unroll
    for (int ks = 0; ks < 4; ++ks) {
      u16x8 raw = *(const u16x8*)(qrow + ks * 32 + lhi * 8);
      float f[8];
#pragma unroll
      for (int j = 0; j < 8; ++j) f[j] = bf2f(raw[j]);
      if (ks >= 2) {
#pragma unroll
        for (int pp = 0; pp < 4; ++pp) {
          int d = ks * 32 + lhi * 8 + 2 * pp;
          int jl = (d - 64) >> 1;
          float ang = (float)qg * powf(10000.f, -(float)jl * (1.f / 32.f));
          float co = cosf(ang), si = sinf(ang);
          float xr = f[2 * pp], xi = f[2 * pp + 1];
          f[2 * pp] = xr * co - xi * si;
          f[2 * pp + 1] = xr * si + xi * co;
        }
      }
      bf16x8 fr;
#pragma unroll
      for (int j = 0; j < 8; ++j) fr[j] = (short)f2bf(f[j] * QSCALE);
      qf[ks] = fr;
    }
  }
  float m_run = -1e30f, l_run = 0.f;

  const int bT = b * 2048;
  const unsigned short* Vbh = Vt + (size_t)(b * 16 + h) * 128 * 2048;

  const unsigned short* pK[4];
  const unsigned short* pV[4];
  int sKst[4];
#pragma unroll
  for (int it = 0; it < 4; ++it) {
    int Lo = it * 4096 + wave * 1024 + lane * 16;
    int r = Lo >> 8;
    int w = (Lo & 255) ^ ((r & 7) << 4);
    int cc = w >> 1;
    if (cc < 64) { pK[it] = kvfull + (size_t)(bT + r) * 3072 + h * 192 + cc; sKst[it] = 64 * 3072; }
    else         { pK[it] = krope  + (size_t)(bT + r) * 64 + (cc - 64);      sKst[it] = 64 * 64; }
    int d = Lo >> 7;
    int w2 = (Lo & 127) ^ ((d & 7) << 4);
    pV[it] = Vbh + (size_t)d * 2048 + (w2 >> 1);
  }

  for (int kt = 0; kt <= s; ++kt) {
#pragma unroll
    for (int it = 0; it < 4; ++it) {
      GLDS16(pK[it], Ks + ((it * 4096 + wave * 1024) >> 1));
      pK[it] += sKst[it];
    }
#pragma unroll
    for (int it = 0; it < 4; ++it) {
      GLDS16(pV[it], Vs + ((it * 4096 + wave * 1024) >> 1));
      pV[it] += 64;
    }
    __syncthreads();

    f32x4 st[4] = {};
    __builtin_amdgcn_s_setprio(1);
#pragma unroll
    for (int ks = 0; ks < 4; ++ks) {
#pragma unroll
      for (int nt = 0; nt < 4; ++nt) {
        int row = nt * 16 + l16;
        int byteoff = row * 256 + ((ks * 64 + lhi * 16) ^ ((l16 & 7) << 4));
        bf16x8 kf = *(const bf16x8*)((const char*)Ks + byteoff);
        st[nt] = __builtin_amdgcn_mfma_f32_16x16x32_bf16(kf, qf[ks], st[nt], 0, 0, 0);
      }
    }
    __builtin_amdgcn_s_setprio(0);

    if (kt == s) {
#pragma unroll
      for (int nt = 0; nt < 4; ++nt)
#pragma unroll
        for (int r = 0; r < 4; ++r) {
          int kg = kt * 64 + nt * 16 + lhi * 4 + r;
          st[nt][r] = (kg <= qg) ? st[nt][r] : -1e30f;
        }
    }
    float mx = -1e30f;
#pragma unroll
    for (int nt = 0; nt < 4; ++nt)
#pragma unroll
      for (int r = 0; r < 4; ++r) mx = fmaxf(mx, st[nt][r]);
    mx = fmaxf(mx, __shfl_xor(mx, 16));
    mx = fmaxf(mx, __shfl_xor(mx, 32));
    if (__ballot(mx > m_run + 8.f)) {
      float mnew = fmaxf(m_run, mx);
      float sc = exp2f(m_run - mnew);
      m_run = mnew;
      l_run *= sc;
#pragma unroll
      for (int dt = 0; dt < 8; ++dt) o_acc[dt] *= sc;
    }
    const float mcur = m_run;
    float sum = 0.f;
#pragma unroll
    for (int nt = 0; nt < 4; ++nt)
#pragma unroll
      for (int r = 0; r < 4; ++r) {
        float p = exp2f(st[nt][r] - mcur);
        st[nt][r] = p;
        sum += p;
      }
    sum += __shfl_xor(sum, 16);
    sum += __shfl_xor(sum, 32);
    l_run += sum;
    bf16x8 pw[2];
    {
      unsigned pk01[4], pk23[4];
#pragma unroll
      for (int nt = 0; nt < 4; ++nt) {
        pk01[nt] = cvtpk(st[nt][0], st[nt][1]);
        pk23[nt] = cvtpk(st[nt][2], st[nt][3]);
      }
#pragma unroll
      for (int k2 = 0; k2 < 2; ++k2) {
        unsigned a0 = pk01[2 * k2], b0 = pk01[2 * k2 + 1];
        unsigned a1 = pk23[2 * k2], b1 = pk23[2 * k2 + 1];
        p32swap(a0, b0); p16swap(a0, b0);
        p32swap(a1, b1); p16swap(a1, b1);
        u32x4 t4 = {a0, a1, b0, b1};
        pw[k2] = *(bf16x8*)&t4;
      }
    }

    __builtin_amdgcn_s_setprio(1);
#pragma unroll
    for (int k2 = 0; k2 < 2; ++k2)
#pragma unroll
      for (int dt = 0; dt < 8; ++dt) {
        int row = dt * 16 + l16;
        int byteoff = row * 128 + ((k2 * 64 + lhi * 16) ^ ((l16 & 7) << 4));
        bf16x8 vf = *(const bf16x8*)((const char*)Vs + byteoff);
        o_acc[dt] = __builtin_amdgcn_mfma_f32_16x16x32_bf16(vf, pw[k2], o_acc[dt], 0, 0, 0);
      }
    __builtin_amdgcn_s_setprio(0);

    __syncthreads();
  }

  {
    float inv = 1.0f / l_run;
    unsigned short* orow = out + (size_t)(b * 2048 + qg) * 2048 + h * 128;
#pragma unroll
    for (int dt = 0; dt < 8; ++dt) {
      unsigned w01 = cvtpk(o_acc[dt][0] * inv, o_acc[dt][1] * inv);
      unsigned w23 = cvtpk(o_acc[dt][2] * inv, o_acc[dt][3] * inv);
      u32x2 st2 = {w01, w23};
      *(u32x2*)(orow + dt * 16 + lhi * 4) = st2;
    }
  }
}

// =====================================================================================
extern "C" void kernel_launch(void* const* d_in, const int* in_sizes, int n_in,
                              void* d_out, int out_size, void* d_ws, size_t ws_size,
                              hipStream_t stream) {
  (void)in_sizes; (void)n_in; (void)out_size; (void)ws_size;
  const float* x      = (const float*)d_in[0];
  const float* w_qa   = (const float*)d_in[2];
  const float* qa_nw  = (const float*)d_in[3];
  const float* w_qb   = (const float*)d_in[4];
  const float* w_kva  = (const float*)d_in[5];
  const float* kva_nw = (const float*)d_in[6];
  const float* w_kvb  = (const float*)d_in[7];
  const float* w_o    = (const float*)d_in[8];
  float* out = (float*)d_out;
  char* ws = (char*)d_ws;

  unsigned short* xb     = (unsigned short*)(ws + 0);
  unsigned short* wqkva  = (unsigned short*)(ws + 16777216);   // [2176][2048]
  unsigned short* wqbb   = (unsigned short*)(ws + 25690112);
  unsigned short* wkvbb  = (unsigned short*)(ws + 31981568);
  unsigned short* wob    = (unsigned short*)(ws + 35127296);
  unsigned short* qkva   = (unsigned short*)(ws + 43515904);   // [4096][2176]
  unsigned short* qfull  = (unsigned short*)(ws + 43515904);   // alias (qkva dead after rms)
  unsigned short* q_c    = (unsigned short*)(ws + 61341696);   // [4096][1536]
  unsigned short* kv_c   = (unsigned short*)(ws + 73924608);   // [4096][512]
  unsigned short* krope  = (unsigned short*)(ws + 78118912);   // [4096][64]
  unsigned short* attno  = (unsigned short*)(ws + 61341696);   // alias (q_c+kv_c dead)
  unsigned short* Vattn  = (unsigned short*)(ws + 78643200);   // [B][H][128][2048]
  unsigned short* kvfull = (unsigned short*)d_out;             // scratch in d_out (k cols only)

  convert_all<<<21248, 256, 0, stream>>>(x, w_qa, w_kva, w_qb, w_kvb, w_o,
                                         xb, wqkva, wqbb, wkvbb, wob);

  gemm_bt<unsigned short><<<32 * 17, 256, 0, stream>>>(xb, wqkva, qkva, 4096, 2176, 2048);

  rms_fused<<<4096, 256, 0, stream>>>(qkva, qa_nw, kva_nw, q_c, kv_c, krope);

  gemm_up<<<1280, 256, 0, stream>>>(q_c, wqbb, qfull, kv_c, wkvbb, kvfull, Vattn);

  flash_attn<<<1024, 256, 0, stream>>>(qfull, kvfull, krope, Vattn, attno);

  gemm_bt<float><<<32 * 16, 256, 0, stream>>>(attno, wob, out, 4096, 2048, 2048);
}